// Round 18
// baseline (156.718 us; speedup 1.0000x reference)
//
#include <hip/hip_runtime.h>
#include <math.h>

#define NN 10000
#define GG 12
#define CC 64
#define AA 3
#define EE 50000
#define LN_EPS 1e-5f
#define MAXDEG 64   // max in-degree cap; Poisson(E/N=5) max ~17, 64 is far beyond

typedef __attribute__((ext_vector_type(4))) float f4;
typedef __attribute__((ext_vector_type(4))) short s4;

union S4U { s4 s; unsigned int w[2]; };
union I2S { int i[2]; s4 s; };

// pack 4 f32 -> 4 bf16 (truncation) in frag element order k0..k3
__device__ __forceinline__ s4 pack4(float k0, float k1, float k2, float k3) {
    S4U t;
    t.w[0] = __builtin_amdgcn_perm(__float_as_uint(k1), __float_as_uint(k0), 0x07060302u);
    t.w[1] = __builtin_amdgcn_perm(__float_as_uint(k3), __float_as_uint(k2), 0x07060302u);
    return t.s;
}
// pack 2 f32 -> one dword [bf16(a) | bf16(b)<<16]
__device__ __forceinline__ unsigned int pack2(float a, float b) {
    return __builtin_amdgcn_perm(__float_as_uint(b), __float_as_uint(a), 0x07060302u);
}

__device__ __forceinline__ f4 mfma_bf16(s4 a, s4 b, f4 c) {
#if __has_builtin(__builtin_amdgcn_mfma_f32_16x16x16bf16_1k)
    return __builtin_amdgcn_mfma_f32_16x16x16bf16_1k(a, b, c, 0, 0, 0);
#else
    asm volatile("v_mfma_f32_16x16x16_bf16 %0, %1, %2, %0" : "+v"(c) : "v"(a), "v"(b));
    return c;
#endif
}

// ---------------- kernel 1: xpack (+ zero cnt + zero hist, fused) ----------------
__global__ __launch_bounds__(256) void xpack(const float* __restrict__ x,
                                             unsigned int* __restrict__ xp,
                                             int* __restrict__ cnt,
                                             int* __restrict__ hist) {
    const int gid = blockIdx.x * 256 + threadIdx.x;
    if (gid < NN) cnt[gid] = 0;
    if (gid < 2 * (MAXDEG + 1)) hist[gid] = 0;      // hist + off

    const int l  = threadIdx.x & 63;
    const int n  = blockIdx.x * 4 + (threadIdx.x >> 6);
    const int lm = l & 15;
    const int lg = l >> 4;

    unsigned int d[8];
    if (lg < 3) {
        const char* xb = (const char*)(x + n * (GG * CC)) + lg * 1024 + lm * 4;
#pragma unroll
        for (int t = 0; t < 4; ++t) {
            const float v0 = *(const float*)(xb + t * 64 + 0 * 256);
            const float v1 = *(const float*)(xb + t * 64 + 1 * 256);
            const float v2 = *(const float*)(xb + t * 64 + 2 * 256);
            const float v3 = *(const float*)(xb + t * 64 + 3 * 256);
            d[2 * t]     = pack2(v0, v1);
            d[2 * t + 1] = pack2(v2, v3);
        }
    } else {
#pragma unroll
        for (int k = 0; k < 8; ++k) d[k] = 0u;
    }
    unsigned int* o = xp + (size_t)n * 512 + l * 8;
    *(uint4*)o       = make_uint4(d[0], d[1], d[2], d[3]);
    *(uint4*)(o + 4) = make_uint4(d[4], d[5], d[6], d[7]);
}

// ---------------- kernel 2: bucket edges by destination; pack e | src<<17 ----------------
__global__ __launch_bounds__(256) void bucket_fill(const int* __restrict__ ei,
                                                   int* __restrict__ cnt,
                                                   int* __restrict__ elist) {
    int e = blockIdx.x * 256 + threadIdx.x;
    if (e < EE) {
        int src = ei[e];
        int dst = ei[EE + e];
        int pos = atomicAdd(&cnt[dst], 1);
        if (pos < MAXDEG) elist[dst * MAXDEG + pos] = e | (src << 17);
    }
}

// ---------------- kernels 2b/2c/2d: degree counting-sort (descending) ----------------
__global__ __launch_bounds__(256) void deg_hist(const int* __restrict__ cnt,
                                                int* __restrict__ hist) {
    int n = blockIdx.x * 256 + threadIdx.x;
    if (n < NN) atomicAdd(&hist[min(cnt[n], MAXDEG)], 1);
}
__global__ __launch_bounds__(64) void deg_prefix(const int* __restrict__ hist,
                                                 int* __restrict__ off) {
    if (threadIdx.x == 0) {
        int acc = 0;
        for (int d = MAXDEG; d >= 0; --d) { off[d] = acc; acc += hist[d]; }
    }
}
__global__ __launch_bounds__(256) void deg_scatter(const int* __restrict__ cnt,
                                                   int* __restrict__ off,
                                                   int* __restrict__ nord) {
    int n = blockIdx.x * 256 + threadIdx.x;
    if (n < NN) {
        int pos = atomicAdd(&off[min(cnt[n], MAXDEG)], 1);
        nord[pos] = n;
    }
}

// ---------------- kernel 3: FUSED conv + LN + MLP + residual ----------------
// wave = node (taken from degree-sorted nord -> uniform deg per block), 4 waves/
// block, no barriers. Edge loop: chunk-3 load-all-upfront (12 VMEM in flight,
// 3 banks = 48 VGPR pipeline state). Epilogue: verified r16 body.
__global__ __launch_bounds__(256) void conv_fused(
    const unsigned int* __restrict__ xp, const float* __restrict__ attr,
    const float* __restrict__ Wk,  const float* __restrict__ cb,
    const float* __restrict__ lnw, const float* __restrict__ lnb,
    const float* __restrict__ W1,  const float* __restrict__ b1,
    const float* __restrict__ W2,  const float* __restrict__ b2,
    const float* __restrict__ ls,  const float* __restrict__ x,
    const int* __restrict__ cnt,   const int* __restrict__ elist,
    const int* __restrict__ nord,
    float* __restrict__ out) {
    __shared__ float scratch[4][1088];   // per-wave: 2 attr slots / [16][68] tile

    const int l  = threadIdx.x & 63;
    const int w  = threadIdx.x >> 6;
    const int n  = nord[blockIdx.x * 4 + w];     // degree-sorted node id
    const int lm = l & 15;
    const int lg = l >> 4;

    const int fbase = (lm < 12 && lg < 3) ? (lm * 36 + lg * 12) : 0;
    const int a1l   = (l < 44) ? l : 43;

    const int deg = min(cnt[n], MAXDEG);
    const int myE = elist[n * MAXDEG + l];

    float wk[3][4];
#pragma unroll
    for (int a = 0; a < 3; ++a)
#pragma unroll
        for (int t = 0; t < 4; ++t)
            wk[a][t] = Wk[a * CC + lm + 16 * t];

    f4 acc[3][4];
#pragma unroll
    for (int a = 0; a < 3; ++a)
#pragma unroll
        for (int t = 0; t < 4; ++t) acc[a][t] = (f4){0.f, 0.f, 0.f, 0.f};

    // 3 register banks (attr 2xf4 + packed-x 2xint4 each)
    f4 Aa0, Aa1, Ab0, Ab1, Ac0, Ac1;
    int4 Xa0, Xa1, Xb0, Xb1, Xc0, Xc1;

#define LOADE(idx, A0, A1, X0, X1)                                              \
    {                                                                           \
        const int p = __builtin_amdgcn_readlane(myE, (idx));                    \
        const char* ab = (const char*)(attr + (size_t)(p & 0x1FFFF) * 432);     \
        A0 = *(const f4*)(ab + 16 * l);                                         \
        A1 = *(const f4*)(ab + 1024 + 16 * a1l);                                \
        const int* xb = (const int*)(xp + (size_t)(p >> 17) * 512 + 8 * l);     \
        X0 = *(const int4*)xb;                                                  \
        X1 = *(const int4*)(xb + 4);                                            \
    }

#define STAGE(slot, A0, A1)                                                     \
    {                                                                           \
        float* sw = &scratch[w][(slot) * 432];                                  \
        *(f4*)(sw + 4 * l) = A0;                                                \
        if (l < 44) *(f4*)(sw + 256 + 4 * l) = A1;                              \
    }

#define COMPUTE(slot, X0, X1)                                                   \
    {                                                                           \
        I2S u0, u1, u2, u3;                                                     \
        u0.i[0] = X0.x; u0.i[1] = X0.y;                                         \
        u1.i[0] = X0.z; u1.i[1] = X0.w;                                         \
        u2.i[0] = X1.x; u2.i[1] = X1.y;                                         \
        u3.i[0] = X1.z; u3.i[1] = X1.w;                                         \
        const float* sr = &scratch[w][(slot) * 432] + fbase;                    \
        const f4 q0 = *(const f4*)(sr);                                         \
        const f4 q1 = *(const f4*)(sr + 4);                                     \
        const f4 q2 = *(const f4*)(sr + 8);                                     \
        const s4 af0 = pack4(q0[0], q0[3], q1[2], q2[1]);                       \
        const s4 af1 = pack4(q0[1], q1[0], q1[3], q2[2]);                       \
        const s4 af2 = pack4(q0[2], q1[1], q2[0], q2[3]);                       \
        acc[0][0] = mfma_bf16(af0, u0.s, acc[0][0]);                            \
        acc[1][0] = mfma_bf16(af1, u0.s, acc[1][0]);                            \
        acc[2][0] = mfma_bf16(af2, u0.s, acc[2][0]);                            \
        acc[0][1] = mfma_bf16(af0, u1.s, acc[0][1]);                            \
        acc[1][1] = mfma_bf16(af1, u1.s, acc[1][1]);                            \
        acc[2][1] = mfma_bf16(af2, u1.s, acc[2][1]);                            \
        acc[0][2] = mfma_bf16(af0, u2.s, acc[0][2]);                            \
        acc[1][2] = mfma_bf16(af1, u2.s, acc[1][2]);                            \
        acc[2][2] = mfma_bf16(af2, u2.s, acc[2][2]);                            \
        acc[0][3] = mfma_bf16(af0, u3.s, acc[0][3]);                            \
        acc[1][3] = mfma_bf16(af1, u3.s, acc[1][3]);                            \
        acc[2][3] = mfma_bf16(af2, u3.s, acc[2][3]);                            \
    }

#define CH1(i) { LOADE((i),Aa0,Aa1,Xa0,Xa1);                                    \
                 STAGE(0,Aa0,Aa1); COMPUTE(0,Xa0,Xa1); }
#define CH2(i) { LOADE((i),Aa0,Aa1,Xa0,Xa1); LOADE((i)+1,Ab0,Ab1,Xb0,Xb1);      \
                 STAGE(0,Aa0,Aa1); COMPUTE(0,Xa0,Xa1);                          \
                 STAGE(1,Ab0,Ab1); COMPUTE(1,Xb0,Xb1); }
#define CH3(i) { LOADE((i),Aa0,Aa1,Xa0,Xa1); LOADE((i)+1,Ab0,Ab1,Xb0,Xb1);      \
                 LOADE((i)+2,Ac0,Ac1,Xc0,Xc1);                                  \
                 STAGE(0,Aa0,Aa1); COMPUTE(0,Xa0,Xa1);                          \
                 STAGE(1,Ab0,Ab1); COMPUTE(1,Xb0,Xb1);                          \
                 STAGE(0,Ac0,Ac1); COMPUTE(0,Xc0,Xc1); }

    int i = 0;
    while (i < deg) {                       // wave-uniform trip count
        const int c = deg - i;
        if (c >= 3)      { CH3(i); i += 3; }
        else if (c == 2) { CH2(i); i += 2; }
        else             { CH1(i); i += 1; }
    }

#undef LOADE
#undef STAGE
#undef COMPUTE
#undef CH1
#undef CH2
#undef CH3

    // ================= fused epilogue (per-wave, no barriers; verified r16) ====
    float* hb = &scratch[w][0];          // now viewed as [16][68] fiber tile

    if (lg < 3) {
#pragma unroll
        for (int t = 0; t < 4; ++t) {
            const float cbT = cb[lm + 16 * t];
#pragma unroll
            for (int r = 0; r < 4; ++r) {
                const float mv = fmaf(acc[0][t][r], wk[0][t],
                                 fmaf(acc[1][t][r], wk[1][t],
                                      acc[2][t][r] * wk[2][t])) + cbT;
                hb[(4 * lg + r) * 68 + lm + 16 * t] = mv;
            }
        }
    }
    *(f4*)(hb + (12 + lg) * 68 + 4 * lm) = (f4){0.f, 0.f, 0.f, 0.f};

    f4 h4[4];
#pragma unroll
    for (int kt = 0; kt < 4; ++kt)
        h4[kt] = *(const f4*)(hb + lm * 68 + 4 * lg + 16 * kt);

    f4 lw4[4], lb4[4];
#pragma unroll
    for (int kt = 0; kt < 4; ++kt) {
        lw4[kt] = *(const f4*)(lnw + 4 * lg + 16 * kt);
        lb4[kt] = *(const f4*)(lnb + 4 * lg + 16 * kt);
    }

    float s = 0.f, s2 = 0.f;
#pragma unroll
    for (int kt = 0; kt < 4; ++kt)
#pragma unroll
        for (int j = 0; j < 4; ++j) {
            const float v = h4[kt][j];
            s += v; s2 += v * v;
        }
    s  += __shfl_xor(s, 16);  s  += __shfl_xor(s, 32);
    s2 += __shfl_xor(s2, 16); s2 += __shfl_xor(s2, 32);
    const float mu  = s * (1.f / 64.f);
    const float inv = rsqrtf(s2 * (1.f / 64.f) - mu * mu + LN_EPS);

    s4 hf[4];
#pragma unroll
    for (int kt = 0; kt < 4; ++kt) {
        const float n0 = (h4[kt][0] - mu) * inv * lw4[kt][0] + lb4[kt][0];
        const float n1 = (h4[kt][1] - mu) * inv * lw4[kt][1] + lb4[kt][1];
        const float n2 = (h4[kt][2] - mu) * inv * lw4[kt][2] + lb4[kt][2];
        const float n3 = (h4[kt][3] - mu) * inv * lw4[kt][3] + lb4[kt][3];
        hf[kt] = pack4(n0, n1, n2, n3);
    }

    f4 z[4];
#pragma unroll
    for (int mt = 0; mt < 4; ++mt) z[mt] = (f4){0.f, 0.f, 0.f, 0.f};
#pragma unroll
    for (int mt = 0; mt < 4; ++mt)
#pragma unroll
        for (int kt = 0; kt < 4; ++kt) {
            const int kb = 4 * lg + 16 * kt;
            const int m  = lm + 16 * mt;
            const s4 wf = pack4(W1[(kb + 0) * CC + m], W1[(kb + 1) * CC + m],
                                W1[(kb + 2) * CC + m], W1[(kb + 3) * CC + m]);
            z[mt] = mfma_bf16(wf, hf[kt], z[mt]);
        }

    s4 gf[4];
#pragma unroll
    for (int mt = 0; mt < 4; ++mt) {
        const f4 b14 = *(const f4*)(b1 + 16 * mt + 4 * lg);
        float g[4];
#pragma unroll
        for (int r = 0; r < 4; ++r) {
            const float zz = z[mt][r] + b14[r];
            g[r] = 0.5f * zz * (1.f + erff(zz * 0.70710678118654752f));
        }
        gf[mt] = pack4(g[0], g[1], g[2], g[3]);
    }

    f4 o[4];
#pragma unroll
    for (int mt = 0; mt < 4; ++mt) o[mt] = (f4){0.f, 0.f, 0.f, 0.f};
#pragma unroll
    for (int mt = 0; mt < 4; ++mt)
#pragma unroll
        for (int kt = 0; kt < 4; ++kt) {
            const int kb = 4 * lg + 16 * kt;
            const int m  = lm + 16 * mt;
            const s4 wf = pack4(W2[(kb + 0) * CC + m], W2[(kb + 1) * CC + m],
                                W2[(kb + 2) * CC + m], W2[(kb + 3) * CC + m]);
            o[mt] = mfma_bf16(wf, gf[kt], o[mt]);
        }

    const int fb2 = lm * 68;
    const int swz = (l & 7) << 2;
#pragma unroll
    for (int mt = 0; mt < 4; ++mt)
#pragma unroll
        for (int r = 0; r < 4; ++r)
            hb[fb2 + ((16 * mt + 4 * lg + r) ^ swz)] = o[mt][r];

    const f4 b2q = *(const f4*)(b2 + 4 * lm);
    const f4 lsq = *(const f4*)(ls + 4 * lm);
    const int f0 = n * GG;

#pragma unroll
    for (int rr = 0; rr < 3; ++rr) {
        const int R   = rr * 4 + lg;         // 0..11
        const int col = 4 * lm;
        const f4 ov = *(const f4*)(&hb[R * 68 + (col ^ ((R & 7) << 2))]);
        const f4 xv = *(const f4*)(x + (size_t)(f0 + R) * CC + col);
        f4 res;
#pragma unroll
        for (int k = 0; k < 4; ++k)
            res[k] = fmaf(lsq[k], ov[k] + b2q[k], xv[k]);
        *(f4*)(out + (size_t)(f0 + R) * CC + col) = res;
    }
}

extern "C" void kernel_launch(void* const* d_in, const int* in_sizes, int n_in,
                              void* d_out, int out_size, void* d_ws, size_t ws_size,
                              hipStream_t stream) {
    const float* x    = (const float*)d_in[0];
    const float* attr = (const float*)d_in[1];
    const float* Wk   = (const float*)d_in[2];
    const float* cb   = (const float*)d_in[3];
    const float* lnw  = (const float*)d_in[4];
    const float* lnb  = (const float*)d_in[5];
    const float* W1   = (const float*)d_in[6];
    const float* b1   = (const float*)d_in[7];
    const float* W2   = (const float*)d_in[8];
    const float* b2   = (const float*)d_in[9];
    const float* ls   = (const float*)d_in[10];
    const int*   ei   = (const int*)d_in[11];
    float* out = (float*)d_out;

    int* cnt   = (int*)d_ws;                                 // NN ints
    int* elist = cnt + NN;                                   // NN*MAXDEG ints
    unsigned int* xp = (unsigned int*)(elist + NN * MAXDEG); // NN*512 dwords
    int* hist  = (int*)(xp + (size_t)NN * 512);              // MAXDEG+1 ints
    int* off   = hist + (MAXDEG + 1);                        // MAXDEG+1 ints
    int* nord  = off + (MAXDEG + 1);                         // NN ints

    xpack<<<NN / 4, 256, 0, stream>>>(x, xp, cnt, hist);     // zeroes cnt + hist/off
    bucket_fill<<<(EE + 255) / 256, 256, 0, stream>>>(ei, cnt, elist);
    deg_hist<<<(NN + 255) / 256, 256, 0, stream>>>(cnt, hist);
    deg_prefix<<<1, 64, 0, stream>>>(hist, off);
    deg_scatter<<<(NN + 255) / 256, 256, 0, stream>>>(cnt, off, nord);
    conv_fused<<<NN / 4, 256, 0, stream>>>(xp, attr, Wk, cb, lnw, lnb, W1, b1,
                                           W2, b2, ls, x, cnt, elist, nord, out);
}

// Round 19
// 69.830 us; speedup vs baseline: 2.2443x; 2.2443x over previous
//
#include <hip/hip_runtime.h>
#include <math.h>

#define NN 10000
#define GG 12
#define CC 64
#define AA 3
#define EE 50000
#define LN_EPS 1e-5f
#define MAXDEG 64   // max in-degree cap; Poisson(E/N=5) max ~17, 64 is far beyond

typedef __attribute__((ext_vector_type(4))) float f4;
typedef __attribute__((ext_vector_type(4))) short s4;

union S4U { s4 s; unsigned int w[2]; };
union I2S { int i[2]; s4 s; };

// pack 4 f32 -> 4 bf16 (truncation) in frag element order k0..k3
__device__ __forceinline__ s4 pack4(float k0, float k1, float k2, float k3) {
    S4U t;
    t.w[0] = __builtin_amdgcn_perm(__float_as_uint(k1), __float_as_uint(k0), 0x07060302u);
    t.w[1] = __builtin_amdgcn_perm(__float_as_uint(k3), __float_as_uint(k2), 0x07060302u);
    return t.s;
}
// pack 2 f32 -> one dword [bf16(a) | bf16(b)<<16]
__device__ __forceinline__ unsigned int pack2(float a, float b) {
    return __builtin_amdgcn_perm(__float_as_uint(b), __float_as_uint(a), 0x07060302u);
}

__device__ __forceinline__ f4 mfma_bf16(s4 a, s4 b, f4 c) {
#if __has_builtin(__builtin_amdgcn_mfma_f32_16x16x16bf16_1k)
    return __builtin_amdgcn_mfma_f32_16x16x16bf16_1k(a, b, c, 0, 0, 0);
#else
    asm volatile("v_mfma_f32_16x16x16_bf16 %0, %1, %2, %0" : "+v"(c) : "v"(a), "v"(b));
    return c;
#endif
}

// async global -> LDS, 16 B per lane; dest = uniform base + lane*16 (linear)
__device__ __forceinline__ void gll(const void* g, void* s) {
    __builtin_amdgcn_global_load_lds(
        (const __attribute__((address_space(1))) void*)g,
        (__attribute__((address_space(3))) void*)s, 16, 0, 0);
}

// ---------------- kernel 1: xpack (+ zero cnt, fused) ----------------
// wave = node. xp[n]: 2KB, lane l owns dwords n*512 + l*8..+7 in exact B-frag
// order; lg==3 (k pad) lanes are zero so conv needs no masking.
__global__ __launch_bounds__(256) void xpack(const float* __restrict__ x,
                                             unsigned int* __restrict__ xp,
                                             int* __restrict__ cnt) {
    const int gid = blockIdx.x * 256 + threadIdx.x;
    if (gid < NN) cnt[gid] = 0;

    const int l  = threadIdx.x & 63;
    const int n  = blockIdx.x * 4 + (threadIdx.x >> 6);
    const int lm = l & 15;
    const int lg = l >> 4;

    unsigned int d[8];
    if (lg < 3) {
        const char* xb = (const char*)(x + n * (GG * CC)) + lg * 1024 + lm * 4;
#pragma unroll
        for (int t = 0; t < 4; ++t) {
            const float v0 = *(const float*)(xb + t * 64 + 0 * 256);
            const float v1 = *(const float*)(xb + t * 64 + 1 * 256);
            const float v2 = *(const float*)(xb + t * 64 + 2 * 256);
            const float v3 = *(const float*)(xb + t * 64 + 3 * 256);
            d[2 * t]     = pack2(v0, v1);
            d[2 * t + 1] = pack2(v2, v3);
        }
    } else {
#pragma unroll
        for (int k = 0; k < 8; ++k) d[k] = 0u;
    }
    unsigned int* o = xp + (size_t)n * 512 + l * 8;
    *(uint4*)o       = make_uint4(d[0], d[1], d[2], d[3]);
    *(uint4*)(o + 4) = make_uint4(d[4], d[5], d[6], d[7]);
}

// ---------------- kernel 2: bucket edges by destination; pack e | src<<17 ----------------
__global__ __launch_bounds__(256) void bucket_fill(const int* __restrict__ ei,
                                                   int* __restrict__ cnt,
                                                   int* __restrict__ elist) {
    int e = blockIdx.x * 256 + threadIdx.x;
    if (e < EE) {
        int src = ei[e];
        int dst = ei[EE + e];
        int pos = atomicAdd(&cnt[dst], 1);
        if (pos < MAXDEG) elist[dst * MAXDEG + pos] = e | (src << 17);
    }
}

// ---------------- kernel 3: FUSED conv + LN + MLP + residual ----------------
// wave = node, 4 waves/block, no barriers (LDS wave-private).
// Edge loop: DEEP ASYNC PIPELINE — per edge 4x global_load_lds (attr 2KB + packed
// x 2KB) into one of 3 rotating 4KB LDS slots; zero VGPR pipeline state. Counted
// s_waitcnt vmcnt(8/4/0) keeps 2 edges (8 loads) in flight across every compute;
// never drains mid-loop. lgkmcnt(0)+sched_barrier before each refill closes the
// ds_read vs async-LDS-write WAR window. Epilogue: verified r16 body.
__global__ __launch_bounds__(256) void conv_fused(
    const unsigned int* __restrict__ xp, const float* __restrict__ attr,
    const float* __restrict__ Wk,  const float* __restrict__ cb,
    const float* __restrict__ lnw, const float* __restrict__ lnb,
    const float* __restrict__ W1,  const float* __restrict__ b1,
    const float* __restrict__ W2,  const float* __restrict__ b2,
    const float* __restrict__ ls,  const float* __restrict__ x,
    const int* __restrict__ cnt,   const int* __restrict__ elist,
    float* __restrict__ out) {
    __shared__ float lsa[4][3][1024];    // 48 KB: 4 waves x 3 async slots x 4KB
                                         // slot: attr bytes [0..2047], xp [2048..4095]
                                         // epilogue reuses wave base as [16][68] tile

    const int l  = threadIdx.x & 63;
    const int w  = threadIdx.x >> 6;
    const int n  = blockIdx.x * 4 + w;
    const int lm = l & 15;
    const int lg = l >> 4;

    const int fbase = (lm < 12 && lg < 3) ? (lm * 36 + lg * 12) : 0;
    const int a1l   = (l < 44) ? l : 43;

    const int deg = min(cnt[n], MAXDEG);
    const int myE = elist[n * MAXDEG + l];

    f4 acc[3][4];
#pragma unroll
    for (int a = 0; a < 3; ++a)
#pragma unroll
        for (int t = 0; t < 4; ++t) acc[a][t] = (f4){0.f, 0.f, 0.f, 0.f};

#define ISSUE(idx, s)                                                           \
    {                                                                           \
        const int p = __builtin_amdgcn_readlane(myE, (idx));                    \
        const char* ab = (const char*)attr + (size_t)(p & 0x1FFFF) * 1728;      \
        const char* xb = (const char*)xp + (size_t)(p >> 17) * 2048;            \
        char* sw = (char*)&lsa[w][s][0];                                        \
        gll(ab + 16 * l,            sw);                                        \
        gll(ab + 1024 + 16 * a1l,   sw + 1024);                                 \
        gll(xb + 32 * l,            sw + 2048);                                 \
        gll(xb + 32 * l + 16,       sw + 3072);                                 \
    }

    // prologue: fill up to 3 slots
    if (deg > 0) ISSUE(0, 0);
    if (deg > 1) ISSUE(1, 1);
    if (deg > 2) ISSUE(2, 2);

    int s = 0;
    for (int i = 0; i < deg; ++i) {
        // wait for edge i's 4 loads only; keep up to 8 younger loads in flight
        const int ahead = deg - 1 - i;
        if (ahead >= 2)      asm volatile("s_waitcnt vmcnt(8)" ::: "memory");
        else if (ahead == 1) asm volatile("s_waitcnt vmcnt(4)" ::: "memory");
        else                 asm volatile("s_waitcnt vmcnt(0)" ::: "memory");
        __builtin_amdgcn_sched_barrier(0);

        const float* sr = &lsa[w][s][0];
        const f4 q0 = *(const f4*)(sr + fbase);
        const f4 q1 = *(const f4*)(sr + fbase + 4);
        const f4 q2 = *(const f4*)(sr + fbase + 8);
        const int4 X0 = *(const int4*)((const char*)sr + 2048 + 16 * l);
        const int4 X1 = *(const int4*)((const char*)sr + 3072 + 16 * l);

        // reads complete (data in VGPR) before this slot is re-targeted
        asm volatile("s_waitcnt lgkmcnt(0)" ::: "memory");
        __builtin_amdgcn_sched_barrier(0);
        if (i + 3 < deg) ISSUE(i + 3, s);

        I2S u0, u1, u2, u3;
        u0.i[0] = X0.x; u0.i[1] = X0.y;
        u1.i[0] = X0.z; u1.i[1] = X0.w;
        u2.i[0] = X1.x; u2.i[1] = X1.y;
        u3.i[0] = X1.z; u3.i[1] = X1.w;
        const s4 af0 = pack4(q0[0], q0[3], q1[2], q2[1]);
        const s4 af1 = pack4(q0[1], q1[0], q1[3], q2[2]);
        const s4 af2 = pack4(q0[2], q1[1], q2[0], q2[3]);
        acc[0][0] = mfma_bf16(af0, u0.s, acc[0][0]);
        acc[1][0] = mfma_bf16(af1, u0.s, acc[1][0]);
        acc[2][0] = mfma_bf16(af2, u0.s, acc[2][0]);
        acc[0][1] = mfma_bf16(af0, u1.s, acc[0][1]);
        acc[1][1] = mfma_bf16(af1, u1.s, acc[1][1]);
        acc[2][1] = mfma_bf16(af2, u1.s, acc[2][1]);
        acc[0][2] = mfma_bf16(af0, u2.s, acc[0][2]);
        acc[1][2] = mfma_bf16(af1, u2.s, acc[1][2]);
        acc[2][2] = mfma_bf16(af2, u2.s, acc[2][2]);
        acc[0][3] = mfma_bf16(af0, u3.s, acc[0][3]);
        acc[1][3] = mfma_bf16(af1, u3.s, acc[1][3]);
        acc[2][3] = mfma_bf16(af2, u3.s, acc[2][3]);

        s = (s == 2) ? 0 : s + 1;
    }

#undef ISSUE

    // ================= fused epilogue (per-wave, no barriers; verified r16) ====
    float wk[3][4];
#pragma unroll
    for (int a = 0; a < 3; ++a)
#pragma unroll
        for (int t = 0; t < 4; ++t)
            wk[a][t] = Wk[a * CC + lm + 16 * t];

    float* hb = &lsa[w][0][0];           // [16][68] fiber tile (1088 floats)

    if (lg < 3) {
#pragma unroll
        for (int t = 0; t < 4; ++t) {
            const float cbT = cb[lm + 16 * t];
#pragma unroll
            for (int r = 0; r < 4; ++r) {
                const float mv = fmaf(acc[0][t][r], wk[0][t],
                                 fmaf(acc[1][t][r], wk[1][t],
                                      acc[2][t][r] * wk[2][t])) + cbT;
                hb[(4 * lg + r) * 68 + lm + 16 * t] = mv;
            }
        }
    }
    *(f4*)(hb + (12 + lg) * 68 + 4 * lm) = (f4){0.f, 0.f, 0.f, 0.f};

    f4 h4[4];
#pragma unroll
    for (int kt = 0; kt < 4; ++kt)
        h4[kt] = *(const f4*)(hb + lm * 68 + 4 * lg + 16 * kt);

    f4 lw4[4], lb4[4];
#pragma unroll
    for (int kt = 0; kt < 4; ++kt) {
        lw4[kt] = *(const f4*)(lnw + 4 * lg + 16 * kt);
        lb4[kt] = *(const f4*)(lnb + 4 * lg + 16 * kt);
    }

    float s1 = 0.f, s2 = 0.f;
#pragma unroll
    for (int kt = 0; kt < 4; ++kt)
#pragma unroll
        for (int j = 0; j < 4; ++j) {
            const float v = h4[kt][j];
            s1 += v; s2 += v * v;
        }
    s1 += __shfl_xor(s1, 16); s1 += __shfl_xor(s1, 32);
    s2 += __shfl_xor(s2, 16); s2 += __shfl_xor(s2, 32);
    const float mu  = s1 * (1.f / 64.f);
    const float inv = rsqrtf(s2 * (1.f / 64.f) - mu * mu + LN_EPS);

    s4 hf[4];
#pragma unroll
    for (int kt = 0; kt < 4; ++kt) {
        const float n0 = (h4[kt][0] - mu) * inv * lw4[kt][0] + lb4[kt][0];
        const float n1 = (h4[kt][1] - mu) * inv * lw4[kt][1] + lb4[kt][1];
        const float n2 = (h4[kt][2] - mu) * inv * lw4[kt][2] + lb4[kt][2];
        const float n3 = (h4[kt][3] - mu) * inv * lw4[kt][3] + lb4[kt][3];
        hf[kt] = pack4(n0, n1, n2, n3);
    }

    f4 z[4];
#pragma unroll
    for (int mt = 0; mt < 4; ++mt) z[mt] = (f4){0.f, 0.f, 0.f, 0.f};
#pragma unroll
    for (int mt = 0; mt < 4; ++mt)
#pragma unroll
        for (int kt = 0; kt < 4; ++kt) {
            const int kb = 4 * lg + 16 * kt;
            const int m  = lm + 16 * mt;
            const s4 wf = pack4(W1[(kb + 0) * CC + m], W1[(kb + 1) * CC + m],
                                W1[(kb + 2) * CC + m], W1[(kb + 3) * CC + m]);
            z[mt] = mfma_bf16(wf, hf[kt], z[mt]);
        }

    s4 gf[4];
#pragma unroll
    for (int mt = 0; mt < 4; ++mt) {
        const f4 b14 = *(const f4*)(b1 + 16 * mt + 4 * lg);
        float g[4];
#pragma unroll
        for (int r = 0; r < 4; ++r) {
            const float zz = z[mt][r] + b14[r];
            g[r] = 0.5f * zz * (1.f + erff(zz * 0.70710678118654752f));
        }
        gf[mt] = pack4(g[0], g[1], g[2], g[3]);
    }

    f4 o[4];
#pragma unroll
    for (int mt = 0; mt < 4; ++mt) o[mt] = (f4){0.f, 0.f, 0.f, 0.f};
#pragma unroll
    for (int mt = 0; mt < 4; ++mt)
#pragma unroll
        for (int kt = 0; kt < 4; ++kt) {
            const int kb = 4 * lg + 16 * kt;
            const int m  = lm + 16 * mt;
            const s4 wf = pack4(W2[(kb + 0) * CC + m], W2[(kb + 1) * CC + m],
                                W2[(kb + 2) * CC + m], W2[(kb + 3) * CC + m]);
            o[mt] = mfma_bf16(wf, gf[kt], o[mt]);
        }

    const int fb2 = lm * 68;
    const int swz = (l & 7) << 2;
#pragma unroll
    for (int mt = 0; mt < 4; ++mt)
#pragma unroll
        for (int r = 0; r < 4; ++r)
            hb[fb2 + ((16 * mt + 4 * lg + r) ^ swz)] = o[mt][r];

    const f4 b2q = *(const f4*)(b2 + 4 * lm);
    const f4 lsq = *(const f4*)(ls + 4 * lm);
    const int f0 = n * GG;

#pragma unroll
    for (int rr = 0; rr < 3; ++rr) {
        const int R   = rr * 4 + lg;         // 0..11
        const int col = 4 * lm;
        const f4 ov = *(const f4*)(&hb[R * 68 + (col ^ ((R & 7) << 2))]);
        const f4 xv = *(const f4*)(x + (size_t)(f0 + R) * CC + col);
        f4 res;
#pragma unroll
        for (int k = 0; k < 4; ++k)
            res[k] = fmaf(lsq[k], ov[k] + b2q[k], xv[k]);
        *(f4*)(out + (size_t)(f0 + R) * CC + col) = res;
    }
}

extern "C" void kernel_launch(void* const* d_in, const int* in_sizes, int n_in,
                              void* d_out, int out_size, void* d_ws, size_t ws_size,
                              hipStream_t stream) {
    const float* x    = (const float*)d_in[0];
    const float* attr = (const float*)d_in[1];
    const float* Wk   = (const float*)d_in[2];
    const float* cb   = (const float*)d_in[3];
    const float* lnw  = (const float*)d_in[4];
    const float* lnb  = (const float*)d_in[5];
    const float* W1   = (const float*)d_in[6];
    const float* b1   = (const float*)d_in[7];
    const float* W2   = (const float*)d_in[8];
    const float* b2   = (const float*)d_in[9];
    const float* ls   = (const float*)d_in[10];
    const int*   ei   = (const int*)d_in[11];
    float* out = (float*)d_out;

    int* cnt   = (int*)d_ws;                                 // NN ints
    int* elist = cnt + NN;                                   // NN*MAXDEG ints
    unsigned int* xp = (unsigned int*)(elist + NN * MAXDEG); // NN*512 dwords (20.5 MB)

    xpack<<<NN / 4, 256, 0, stream>>>(x, xp, cnt);           // also zeroes cnt
    bucket_fill<<<(EE + 255) / 256, 256, 0, stream>>>(ei, cnt, elist);
    conv_fused<<<NN / 4, 256, 0, stream>>>(xp, attr, Wk, cb, lnw, lnb, W1, b1,
                                           W2, b2, ls, x, cnt, elist, out);
}

// Round 20
// 69.613 us; speedup vs baseline: 2.2513x; 1.0031x over previous
//
#include <hip/hip_runtime.h>
#include <math.h>

#define NN 10000
#define GG 12
#define CC 64
#define AA 3
#define EE 50000
#define LN_EPS 1e-5f
#define MAXDEG 64   // max in-degree cap; Poisson(E/N=5) max ~17, 64 is far beyond

typedef __attribute__((ext_vector_type(4))) float f4;
typedef __attribute__((ext_vector_type(4))) short s4;

union S4U { s4 s; unsigned int w[2]; };
union I2S { int i[2]; s4 s; };

// pack 4 f32 -> 4 bf16 (truncation) in frag element order k0..k3
__device__ __forceinline__ s4 pack4(float k0, float k1, float k2, float k3) {
    S4U t;
    t.w[0] = __builtin_amdgcn_perm(__float_as_uint(k1), __float_as_uint(k0), 0x07060302u);
    t.w[1] = __builtin_amdgcn_perm(__float_as_uint(k3), __float_as_uint(k2), 0x07060302u);
    return t.s;
}
// pack 2 f32 -> one dword [bf16(a) | bf16(b)<<16]
__device__ __forceinline__ unsigned int pack2(float a, float b) {
    return __builtin_amdgcn_perm(__float_as_uint(b), __float_as_uint(a), 0x07060302u);
}

__device__ __forceinline__ f4 mfma_bf16(s4 a, s4 b, f4 c) {
#if __has_builtin(__builtin_amdgcn_mfma_f32_16x16x16bf16_1k)
    return __builtin_amdgcn_mfma_f32_16x16x16bf16_1k(a, b, c, 0, 0, 0);
#else
    asm volatile("v_mfma_f32_16x16x16_bf16 %0, %1, %2, %0" : "+v"(c) : "v"(a), "v"(b));
    return c;
#endif
}

// async global -> LDS, 16 B per lane; dest = uniform base + lane*16 (linear)
__device__ __forceinline__ void gll(const void* g, void* s) {
    __builtin_amdgcn_global_load_lds(
        (const __attribute__((address_space(1))) void*)g,
        (__attribute__((address_space(3))) void*)s, 16, 0, 0);
}

// ---------------- kernel 1: xpack (+ zero cnt, fused) ----------------
// wave = node. xp[n]: 2KB, lane l owns dwords n*512 + l*8..+7 in exact B-frag
// order; lg==3 (k pad) lanes are zero so conv needs no masking.
__global__ __launch_bounds__(256) void xpack(const float* __restrict__ x,
                                             unsigned int* __restrict__ xp,
                                             int* __restrict__ cnt) {
    const int gid = blockIdx.x * 256 + threadIdx.x;
    if (gid < NN) cnt[gid] = 0;

    const int l  = threadIdx.x & 63;
    const int n  = blockIdx.x * 4 + (threadIdx.x >> 6);
    const int lm = l & 15;
    const int lg = l >> 4;

    unsigned int d[8];
    if (lg < 3) {
        const char* xb = (const char*)(x + n * (GG * CC)) + lg * 1024 + lm * 4;
#pragma unroll
        for (int t = 0; t < 4; ++t) {
            const float v0 = *(const float*)(xb + t * 64 + 0 * 256);
            const float v1 = *(const float*)(xb + t * 64 + 1 * 256);
            const float v2 = *(const float*)(xb + t * 64 + 2 * 256);
            const float v3 = *(const float*)(xb + t * 64 + 3 * 256);
            d[2 * t]     = pack2(v0, v1);
            d[2 * t + 1] = pack2(v2, v3);
        }
    } else {
#pragma unroll
        for (int k = 0; k < 8; ++k) d[k] = 0u;
    }
    unsigned int* o = xp + (size_t)n * 512 + l * 8;
    *(uint4*)o       = make_uint4(d[0], d[1], d[2], d[3]);
    *(uint4*)(o + 4) = make_uint4(d[4], d[5], d[6], d[7]);
}

// ---------------- kernel 2: bucket edges by destination; pack e | src<<17 ----------------
__global__ __launch_bounds__(256) void bucket_fill(const int* __restrict__ ei,
                                                   int* __restrict__ cnt,
                                                   int* __restrict__ elist) {
    int e = blockIdx.x * 256 + threadIdx.x;
    if (e < EE) {
        int src = ei[e];
        int dst = ei[EE + e];
        int pos = atomicAdd(&cnt[dst], 1);
        if (pos < MAXDEG) elist[dst * MAXDEG + pos] = e | (src << 17);
    }
}

// ---------------- kernel 3: FUSED conv + LN + MLP + residual ----------------
// wave = node, 4 waves/block. Edge loop: deep async pipeline (unchanged r19,
// counted vmcnt, 3 rotating 4KB LDS slots, zero VGPR pipeline state).
// NEW: W1/W2 MFMA fragment tables are built ONCE PER BLOCK cooperatively into
// the dead slot-2 regions (8KB each; wave w packs mt=w quarter), then GEMM1/2
// fetch fragments via single ds_read_b64 — weight global requests drop 4x
// (2048 -> 512 per block; -3.8M requests kernel-wide).
__global__ __launch_bounds__(256) void conv_fused(
    const unsigned int* __restrict__ xp, const float* __restrict__ attr,
    const float* __restrict__ Wk,  const float* __restrict__ cb,
    const float* __restrict__ lnw, const float* __restrict__ lnb,
    const float* __restrict__ W1,  const float* __restrict__ b1,
    const float* __restrict__ W2,  const float* __restrict__ b2,
    const float* __restrict__ ls,  const float* __restrict__ x,
    const int* __restrict__ cnt,   const int* __restrict__ elist,
    float* __restrict__ out) {
    __shared__ float lsa[4][3][1024];    // 48 KB: 4 waves x 3 async slots x 4KB
                                         // edge loop: wave-private slot rotation
                                         // epilogue: hb tile = slot0+256B of slot1;
                                         //   W1 table = lsa[0..1][2], W2 = lsa[2..3][2]

    const int l  = threadIdx.x & 63;
    const int w  = threadIdx.x >> 6;
    const int n  = blockIdx.x * 4 + w;
    const int lm = l & 15;
    const int lg = l >> 4;

    const int fbase = (lm < 12 && lg < 3) ? (lm * 36 + lg * 12) : 0;
    const int a1l   = (l < 44) ? l : 43;

    const int deg = min(cnt[n], MAXDEG);
    const int myE = elist[n * MAXDEG + l];

    f4 acc[3][4];
#pragma unroll
    for (int a = 0; a < 3; ++a)
#pragma unroll
        for (int t = 0; t < 4; ++t) acc[a][t] = (f4){0.f, 0.f, 0.f, 0.f};

#define ISSUE(idx, s)                                                           \
    {                                                                           \
        const int p = __builtin_amdgcn_readlane(myE, (idx));                    \
        const char* ab = (const char*)attr + (size_t)(p & 0x1FFFF) * 1728;      \
        const char* xb = (const char*)xp + (size_t)(p >> 17) * 2048;            \
        char* sw = (char*)&lsa[w][s][0];                                        \
        gll(ab + 16 * l,            sw);                                        \
        gll(ab + 1024 + 16 * a1l,   sw + 1024);                                 \
        gll(xb + 32 * l,            sw + 2048);                                 \
        gll(xb + 32 * l + 16,       sw + 3072);                                 \
    }

    // prologue: fill up to 3 slots
    if (deg > 0) ISSUE(0, 0);
    if (deg > 1) ISSUE(1, 1);
    if (deg > 2) ISSUE(2, 2);

    int s = 0;
    for (int i = 0; i < deg; ++i) {
        // wait for edge i's 4 loads only; keep up to 8 younger loads in flight
        const int ahead = deg - 1 - i;
        if (ahead >= 2)      asm volatile("s_waitcnt vmcnt(8)" ::: "memory");
        else if (ahead == 1) asm volatile("s_waitcnt vmcnt(4)" ::: "memory");
        else                 asm volatile("s_waitcnt vmcnt(0)" ::: "memory");
        __builtin_amdgcn_sched_barrier(0);

        const float* sr = &lsa[w][s][0];
        const f4 q0 = *(const f4*)(sr + fbase);
        const f4 q1 = *(const f4*)(sr + fbase + 4);
        const f4 q2 = *(const f4*)(sr + fbase + 8);
        const int4 X0 = *(const int4*)((const char*)sr + 2048 + 16 * l);
        const int4 X1 = *(const int4*)((const char*)sr + 3072 + 16 * l);

        // reads complete (data in VGPR) before this slot is re-targeted
        asm volatile("s_waitcnt lgkmcnt(0)" ::: "memory");
        __builtin_amdgcn_sched_barrier(0);
        if (i + 3 < deg) ISSUE(i + 3, s);

        I2S u0, u1, u2, u3;
        u0.i[0] = X0.x; u0.i[1] = X0.y;
        u1.i[0] = X0.z; u1.i[1] = X0.w;
        u2.i[0] = X1.x; u2.i[1] = X1.y;
        u3.i[0] = X1.z; u3.i[1] = X1.w;
        const s4 af0 = pack4(q0[0], q0[3], q1[2], q2[1]);
        const s4 af1 = pack4(q0[1], q1[0], q1[3], q2[2]);
        const s4 af2 = pack4(q0[2], q1[1], q2[0], q2[3]);
        acc[0][0] = mfma_bf16(af0, u0.s, acc[0][0]);
        acc[1][0] = mfma_bf16(af1, u0.s, acc[1][0]);
        acc[2][0] = mfma_bf16(af2, u0.s, acc[2][0]);
        acc[0][1] = mfma_bf16(af0, u1.s, acc[0][1]);
        acc[1][1] = mfma_bf16(af1, u1.s, acc[1][1]);
        acc[2][1] = mfma_bf16(af2, u1.s, acc[2][1]);
        acc[0][2] = mfma_bf16(af0, u2.s, acc[0][2]);
        acc[1][2] = mfma_bf16(af1, u2.s, acc[1][2]);
        acc[2][2] = mfma_bf16(af2, u2.s, acc[2][2]);
        acc[0][3] = mfma_bf16(af0, u3.s, acc[0][3]);
        acc[1][3] = mfma_bf16(af1, u3.s, acc[1][3]);
        acc[2][3] = mfma_bf16(af2, u3.s, acc[2][3]);

        s = (s == 2) ? 0 : s + 1;
    }

#undef ISSUE

    // ---- cooperative W1/W2 fragment table staging (block-shared, bf16) ----
    // Table entry (mt,kt,lane) = 8B s4 at region[mt>>1] + (mt&1)*2048 + kt*512 + lane*8.
    // W1 regions: lsa[0][2], lsa[1][2]; W2: lsa[2][2], lsa[3][2].
    // Wave w packs mt = w for both matrices (identical pack4 to the verified r16 path).
    __syncthreads();                 // all waves done with their private slots
    {
        const int mt = w;
        char* d1 = (char*)&lsa[mt >> 1][2][0]     + (mt & 1) * 2048 + l * 8;
        char* d2 = (char*)&lsa[2 + (mt >> 1)][2][0] + (mt & 1) * 2048 + l * 8;
        const int m = lm + 16 * mt;
#pragma unroll
        for (int kt = 0; kt < 4; ++kt) {
            const int kb = 4 * lg + 16 * kt;
            const s4 f1 = pack4(W1[(kb + 0) * CC + m], W1[(kb + 1) * CC + m],
                                W1[(kb + 2) * CC + m], W1[(kb + 3) * CC + m]);
            const s4 f2 = pack4(W2[(kb + 0) * CC + m], W2[(kb + 1) * CC + m],
                                W2[(kb + 2) * CC + m], W2[(kb + 3) * CC + m]);
            *(s4*)(d1 + kt * 512) = f1;
            *(s4*)(d2 + kt * 512) = f2;
        }
    }
    __syncthreads();

    // ================= fused epilogue (verified r16 body; weights from LDS) ====
    float wk[3][4];
#pragma unroll
    for (int a = 0; a < 3; ++a)
#pragma unroll
        for (int t = 0; t < 4; ++t)
            wk[a][t] = Wk[a * CC + lm + 16 * t];

    float* hb = &lsa[w][0][0];           // [16][68] fiber tile (slot0 + 256B of slot1)

    if (lg < 3) {
#pragma unroll
        for (int t = 0; t < 4; ++t) {
            const float cbT = cb[lm + 16 * t];
#pragma unroll
            for (int r = 0; r < 4; ++r) {
                const float mv = fmaf(acc[0][t][r], wk[0][t],
                                 fmaf(acc[1][t][r], wk[1][t],
                                      acc[2][t][r] * wk[2][t])) + cbT;
                hb[(4 * lg + r) * 68 + lm + 16 * t] = mv;
            }
        }
    }
    *(f4*)(hb + (12 + lg) * 68 + 4 * lm) = (f4){0.f, 0.f, 0.f, 0.f};

    f4 h4[4];
#pragma unroll
    for (int kt = 0; kt < 4; ++kt)
        h4[kt] = *(const f4*)(hb + lm * 68 + 4 * lg + 16 * kt);

    f4 lw4[4], lb4[4];
#pragma unroll
    for (int kt = 0; kt < 4; ++kt) {
        lw4[kt] = *(const f4*)(lnw + 4 * lg + 16 * kt);
        lb4[kt] = *(const f4*)(lnb + 4 * lg + 16 * kt);
    }

    float s1 = 0.f, s2 = 0.f;
#pragma unroll
    for (int kt = 0; kt < 4; ++kt)
#pragma unroll
        for (int j = 0; j < 4; ++j) {
            const float v = h4[kt][j];
            s1 += v; s2 += v * v;
        }
    s1 += __shfl_xor(s1, 16); s1 += __shfl_xor(s1, 32);
    s2 += __shfl_xor(s2, 16); s2 += __shfl_xor(s2, 32);
    const float mu  = s1 * (1.f / 64.f);
    const float inv = rsqrtf(s2 * (1.f / 64.f) - mu * mu + LN_EPS);

    s4 hf[4];
#pragma unroll
    for (int kt = 0; kt < 4; ++kt) {
        const float n0 = (h4[kt][0] - mu) * inv * lw4[kt][0] + lb4[kt][0];
        const float n1 = (h4[kt][1] - mu) * inv * lw4[kt][1] + lb4[kt][1];
        const float n2 = (h4[kt][2] - mu) * inv * lw4[kt][2] + lb4[kt][2];
        const float n3 = (h4[kt][3] - mu) * inv * lw4[kt][3] + lb4[kt][3];
        hf[kt] = pack4(n0, n1, n2, n3);
    }

    // GEMM1: W1 fragments via ds_read_b64 from the block-shared table
    f4 z[4];
#pragma unroll
    for (int mt = 0; mt < 4; ++mt) z[mt] = (f4){0.f, 0.f, 0.f, 0.f};
#pragma unroll
    for (int mt = 0; mt < 4; ++mt) {
        const char* tb = (const char*)&lsa[mt >> 1][2][0] + (mt & 1) * 2048 + l * 8;
#pragma unroll
        for (int kt = 0; kt < 4; ++kt) {
            const s4 wf = *(const s4*)(tb + kt * 512);
            z[mt] = mfma_bf16(wf, hf[kt], z[mt]);
        }
    }

    s4 gf[4];
#pragma unroll
    for (int mt = 0; mt < 4; ++mt) {
        const f4 b14 = *(const f4*)(b1 + 16 * mt + 4 * lg);
        float g[4];
#pragma unroll
        for (int r = 0; r < 4; ++r) {
            const float zz = z[mt][r] + b14[r];
            g[r] = 0.5f * zz * (1.f + erff(zz * 0.70710678118654752f));
        }
        gf[mt] = pack4(g[0], g[1], g[2], g[3]);
    }

    // GEMM2: W2 fragments via ds_read_b64
    f4 o[4];
#pragma unroll
    for (int mt = 0; mt < 4; ++mt) o[mt] = (f4){0.f, 0.f, 0.f, 0.f};
#pragma unroll
    for (int mt = 0; mt < 4; ++mt) {
        const char* tb = (const char*)&lsa[2 + (mt >> 1)][2][0] + (mt & 1) * 2048 + l * 8;
#pragma unroll
        for (int kt = 0; kt < 4; ++kt) {
            const s4 wf = *(const s4*)(tb + kt * 512);
            o[mt] = mfma_bf16(wf, gf[kt], o[mt]);
        }
    }

    const int fb2 = lm * 68;
    const int swz = (l & 7) << 2;
#pragma unroll
    for (int mt = 0; mt < 4; ++mt)
#pragma unroll
        for (int r = 0; r < 4; ++r)
            hb[fb2 + ((16 * mt + 4 * lg + r) ^ swz)] = o[mt][r];

    const f4 b2q = *(const f4*)(b2 + 4 * lm);
    const f4 lsq = *(const f4*)(ls + 4 * lm);
    const int f0 = n * GG;

#pragma unroll
    for (int rr = 0; rr < 3; ++rr) {
        const int R   = rr * 4 + lg;         // 0..11
        const int col = 4 * lm;
        const f4 ov = *(const f4*)(&hb[R * 68 + (col ^ ((R & 7) << 2))]);
        const f4 xv = *(const f4*)(x + (size_t)(f0 + R) * CC + col);
        f4 res;
#pragma unroll
        for (int k = 0; k < 4; ++k)
            res[k] = fmaf(lsq[k], ov[k] + b2q[k], xv[k]);
        *(f4*)(out + (size_t)(f0 + R) * CC + col) = res;
    }
}

extern "C" void kernel_launch(void* const* d_in, const int* in_sizes, int n_in,
                              void* d_out, int out_size, void* d_ws, size_t ws_size,
                              hipStream_t stream) {
    const float* x    = (const float*)d_in[0];
    const float* attr = (const float*)d_in[1];
    const float* Wk   = (const float*)d_in[2];
    const float* cb   = (const float*)d_in[3];
    const float* lnw  = (const float*)d_in[4];
    const float* lnb  = (const float*)d_in[5];
    const float* W1   = (const float*)d_in[6];
    const float* b1   = (const float*)d_in[7];
    const float* W2   = (const float*)d_in[8];
    const float* b2   = (const float*)d_in[9];
    const float* ls   = (const float*)d_in[10];
    const int*   ei   = (const int*)d_in[11];
    float* out = (float*)d_out;

    int* cnt   = (int*)d_ws;                                 // NN ints
    int* elist = cnt + NN;                                   // NN*MAXDEG ints
    unsigned int* xp = (unsigned int*)(elist + NN * MAXDEG); // NN*512 dwords (20.5 MB)

    xpack<<<NN / 4, 256, 0, stream>>>(x, xp, cnt);           // also zeroes cnt
    bucket_fill<<<(EE + 255) / 256, 256, 0, stream>>>(ei, cnt, elist);
    conv_fused<<<NN / 4, 256, 0, stream>>>(xp, attr, Wk, cb, lnw, lnb, W1, b1,
                                           W2, b2, ls, x, cnt, elist, out);
}